// Round 18
// baseline (242.664 us; speedup 1.0000x reference)
//
#include <hip/hip_runtime.h>
#include <math.h>

#define NN 50000
#define NE 800000
#define NEG 0.2f
#define NB 196  // ceil(NN/256)

typedef __attribute__((ext_vector_type(4))) float f32x4;
typedef __attribute__((ext_vector_type(8))) _Float16 half8;

#define PAIR(v, k) (__builtin_shufflevector(v, v, 2 * (k), 2 * (k) + 1))

// ---- repack W [128][256] f32 -> MFMA fragment order [ks][ct][lane][8], fp16 ----
__global__ __launch_bounds__(256) void cvt_w(
    const float* __restrict__ Ws, const float* __restrict__ Wd,
    _Float16* __restrict__ Sfrag, _Float16* __restrict__ Dfrag)
{
    const int idx = blockIdx.x * 256 + threadIdx.x;   // 0..32767
    const float* W = blockIdx.y ? Wd : Ws;
    _Float16* o = blockIdx.y ? Dfrag : Sfrag;
    const int j  = idx & 7;
    const int l  = (idx >> 3) & 63;
    const int ct = (idx >> 9) & 15;
    const int ks = idx >> 13;
    const int k   = ks * 32 + ((l >> 4) << 3) + j;
    const int col = (ct << 4) + (l & 15);
    o[idx] = (_Float16)W[(size_t)k * 256 + col];
}

// ---- dual GEMM, ONE pass: both S and D projections per block (feat read once).
//      W ks-chunks staged in LDS (16 KB each = 4+4 uint4/thread). fp16 outputs.
__global__ __launch_bounds__(256) void gemm_mfma(
    const float* __restrict__ feat,
    const _Float16* __restrict__ WfS, const float* __restrict__ bS,
    _Float16* __restrict__ outS,
    const _Float16* __restrict__ WfD, const float* __restrict__ bD,
    _Float16* __restrict__ outD)
{
    __shared__ uint4 ldsW[2][1024];   // [0]=S chunk, [1]=D chunk (16 KB each)

    const int tid = threadIdx.x;
    const int w   = tid >> 6;        // wave -> rows w*16..+15
    const int l   = tid & 63;
    const int r16 = l & 15;          // A row within tile
    const int kg  = l >> 4;          // k-group (8 wide)
    const int row0 = blockIdx.x * 64;

    int arow = row0 + w * 16 + r16;
    if (arow >= NN) arow = NN - 1;   // clamp (stores guarded)

    f32x4 accS[16], accD[16];
#pragma unroll
    for (int ct = 0; ct < 16; ++ct) {
        accS[ct] = (f32x4){0.f, 0.f, 0.f, 0.f};
        accD[ct] = (f32x4){0.f, 0.f, 0.f, 0.f};
    }

    for (int ks = 0; ks < 4; ++ks) {
        // ---- issue staging + A loads (overlap previous chunk's MFMAs) ----
        const uint4* srcS = reinterpret_cast<const uint4*>(WfS + ks * 8192);
        const uint4* srcD = reinterpret_cast<const uint4*>(WfD + ks * 8192);
        const uint4 a0 = srcS[tid],       a1 = srcS[256 + tid];
        const uint4 a2 = srcS[512 + tid], a3 = srcS[768 + tid];
        const uint4 d0 = srcD[tid],       d1 = srcD[256 + tid];
        const uint4 d2 = srcD[512 + tid], d3 = srcD[768 + tid];
        const float4 fa = *reinterpret_cast<const float4*>(
            &feat[(size_t)arow * 128 + ks * 32 + kg * 8]);
        const float4 fb = *reinterpret_cast<const float4*>(
            &feat[(size_t)arow * 128 + ks * 32 + kg * 8 + 4]);

        __syncthreads();             // previous chunk fully consumed
        ldsW[0][tid] = a0; ldsW[0][256 + tid] = a1;
        ldsW[0][512 + tid] = a2; ldsW[0][768 + tid] = a3;
        ldsW[1][tid] = d0; ldsW[1][256 + tid] = d1;
        ldsW[1][512 + tid] = d2; ldsW[1][768 + tid] = d3;
        __syncthreads();

        // ---- convert A to fp16 in-register ----
        half8 ah;
        ah[0] = (_Float16)fa.x; ah[1] = (_Float16)fa.y;
        ah[2] = (_Float16)fa.z; ah[3] = (_Float16)fa.w;
        ah[4] = (_Float16)fb.x; ah[5] = (_Float16)fb.y;
        ah[6] = (_Float16)fb.z; ah[7] = (_Float16)fb.w;

        const half8* bpS = reinterpret_cast<const half8*>(&ldsW[0][0]);
        const half8* bpD = reinterpret_cast<const half8*>(&ldsW[1][0]);
#pragma unroll
        for (int ct = 0; ct < 16; ++ct) {
            const half8 bhS = bpS[ct * 64 + l];   // ds_read_b128, conflict-free
            const half8 bhD = bpD[ct * 64 + l];
            accS[ct] = __builtin_amdgcn_mfma_f32_16x16x32_f16(ah, bhS, accS[ct], 0, 0, 0);
            accD[ct] = __builtin_amdgcn_mfma_f32_16x16x32_f16(ah, bhD, accD[ct], 0, 0, 0);
        }
    }

    // D layout: col = ct*16 + (lane&15), row = w*16 + (lane>>4)*4 + reg
    const int orow0 = row0 + w * 16 + kg * 4;
#pragma unroll
    for (int ct = 0; ct < 16; ++ct) {
        const int col = ct * 16 + r16;
        const float biasS = bS[col];
        const float biasD = bD[col];
#pragma unroll
        for (int reg = 0; reg < 4; ++reg) {
            const int orow = orow0 + reg;
            if (orow < NN) {
                outS[(size_t)orow * 256 + col] = (_Float16)(accS[ct][reg] + biasS);
                outD[(size_t)orow * 256 + col] = (_Float16)(accD[ct][reg] + biasD);
            }
        }
    }
}

// ---------------- CSR build ----------------
__global__ void count_deg(const int* __restrict__ dst, int* __restrict__ deg)
{
    int e = blockIdx.x * blockDim.x + threadIdx.x;
    if (e < NE) atomicAdd(&deg[dst[e]], 1);
}

__global__ __launch_bounds__(256) void deg_blocksum(const int* __restrict__ deg,
                                                    int* __restrict__ bsum)
{
    int i = blockIdx.x * 256 + threadIdx.x;
    int v = (i < NN) ? deg[i] : 0;
#pragma unroll
    for (int off = 32; off; off >>= 1) v += __shfl_xor(v, off);
    __shared__ int ws[4];
    if ((threadIdx.x & 63) == 0) ws[threadIdx.x >> 6] = v;
    __syncthreads();
    if (threadIdx.x == 0) bsum[blockIdx.x] = ws[0] + ws[1] + ws[2] + ws[3];
}

__global__ __launch_bounds__(256) void scan_bsum(int* __restrict__ bsum)
{
    __shared__ int tmp[256];
    int t = threadIdx.x;
    int orig = (t < NB) ? bsum[t] : 0;
    tmp[t] = orig;
    __syncthreads();
    for (int off = 1; off < 256; off <<= 1) {
        int v = (t >= off) ? tmp[t - off] : 0;
        __syncthreads();
        tmp[t] += v;
        __syncthreads();
    }
    if (t < NB) bsum[t] = tmp[t] - orig;  // exclusive prefix
}

__global__ __launch_bounds__(256) void write_rows(const int* __restrict__ deg,
                                                  const int* __restrict__ bpre,
                                                  int* __restrict__ row_start,
                                                  int* __restrict__ cursor)
{
    int i = blockIdx.x * 256 + threadIdx.x;
    int d = (i < NN) ? deg[i] : 0;
    int lane = threadIdx.x & 63, w = threadIdx.x >> 6;
    int x = d;
#pragma unroll
    for (int off = 1; off < 64; off <<= 1) {
        int v = __shfl_up(x, off);
        if (lane >= off) x += v;
    }
    __shared__ int wsum[4];
    if (lane == 63) wsum[w] = x;
    __syncthreads();
    int woff = 0;
#pragma unroll
    for (int k = 0; k < 4; ++k)
        if (k < w) woff += wsum[k];
    if (i < NN) {
        int rs = bpre[blockIdx.x] + woff + x - d;
        row_start[i] = rs;
        cursor[i] = rs;
    }
    if (blockIdx.x == 0 && threadIdx.x == 0) row_start[NN] = NE;
}

// cursor pre-initialized to row_start values -> absolute positions
__global__ void scatter_src(const int* __restrict__ src, const int* __restrict__ dst,
                            int* __restrict__ cursor, int* __restrict__ src_sorted)
{
    int e = blockIdx.x * blockDim.x + threadIdx.x;
    if (e < NE) {
        int pos = atomicAdd(&cursor[dst[e]], 1);
        src_sorted[pos] = src[e];
    }
}

// ---- Layer-1 fused: WAVE = NODE, 32 lanes per edge (2 edges/iter, x2 unroll).
//      lane = 8 contiguous dims (16B fp16 load); packed-fp16 score; f32 accum.
__global__ __launch_bounds__(256) void gat1_fused(
    const _Float16* __restrict__ hs, const _Float16* __restrict__ hd,
    const float* __restrict__ attn, const int* __restrict__ src_sorted,
    const int* __restrict__ row_start,
    const float* __restrict__ W2s, const float* __restrict__ b2s,
    const float* __restrict__ W2d, const float* __restrict__ b2d,
    float* __restrict__ hs2, float* __restrict__ hd2)
{
    const int n = blockIdx.x * 4 + (threadIdx.x >> 6);   // NN % 4 == 0
    const int lane = threadIdx.x & 63;
    const int half_id = lane >> 5;     // which edge of the pair
    const int sl = lane & 31;          // dims sl*8 .. sl*8+7 (head = sl>>3)
    const int beg = row_start[n], end_ = row_start[n + 1];

    // this lane's 8 dims of attn (converted) and hd (already fp16)
    const float4 af0 = *reinterpret_cast<const float4*>(&attn[sl * 8 + 0]);
    const float4 af1 = *reinterpret_cast<const float4*>(&attn[sl * 8 + 4]);
    half8 ah;
    ah[0] = (_Float16)af0.x; ah[1] = (_Float16)af0.y; ah[2] = (_Float16)af0.z; ah[3] = (_Float16)af0.w;
    ah[4] = (_Float16)af1.x; ah[5] = (_Float16)af1.y; ah[6] = (_Float16)af1.z; ah[7] = (_Float16)af1.w;
    const half8 yh = *reinterpret_cast<const half8*>(&hd[(size_t)n * 256 + sl * 8]);
    const _Float16 NEGH = (_Float16)NEG;

    float m = -INFINITY, den = 0.0f;
    float acc[8];
#pragma unroll
    for (int j = 0; j < 8; ++j) acc[j] = 0.0f;

#define SCORE(xh, p)                                                         \
    {                                                                        \
        half8 t = xh + yh;                                                   \
        half8 tn = t * NEGH;                                                 \
        t = __builtin_elementwise_max(t, tn);                                \
        p = __builtin_amdgcn_fdot2(PAIR(t, 0), PAIR(ah, 0), 0.0f, false);    \
        p = __builtin_amdgcn_fdot2(PAIR(t, 1), PAIR(ah, 1), p, false);       \
        p = __builtin_amdgcn_fdot2(PAIR(t, 2), PAIR(ah, 2), p, false);       \
        p = __builtin_amdgcn_fdot2(PAIR(t, 3), PAIR(ah, 3), p, false);       \
    }
#define UPDATE(xh, wv)                                                       \
    {                                                                        \
        den += wv;                                                           \
        _Pragma("unroll")                                                    \
        for (int j = 0; j < 8; ++j)                                          \
            acc[j] = fmaf(wv, (float)xh[j], acc[j]);                         \
    }
#define RESCALE(p)                                                           \
    if (p > m + 8.0f) {                                                      \
        const float rs = __expf(m - p);                                      \
        den *= rs;                                                           \
        _Pragma("unroll")                                                    \
        for (int j = 0; j < 8; ++j) acc[j] *= rs;                            \
        m = p;                                                               \
    }

    int base = beg;
    // -------- main loop: 4 edges per iter (2 per half-wave, 2 gathers in flight) ----
    for (; base + 3 < end_; base += 4) {
        const int sA = src_sorted[base + half_id];
        const int sB = src_sorted[base + 2 + half_id];
        const half8 xA = *reinterpret_cast<const half8*>(&hs[(size_t)sA * 256 + sl * 8]);
        const half8 xB = *reinterpret_cast<const half8*>(&hs[(size_t)sB * 256 + sl * 8]);
        float pA, pB;
        SCORE(xA, pA)
        SCORE(xB, pB)
        pA += __shfl_xor(pA, 1);  pB += __shfl_xor(pB, 1);
        pA += __shfl_xor(pA, 2);  pB += __shfl_xor(pB, 2);
        pA += __shfl_xor(pA, 4);  pB += __shfl_xor(pB, 4);
        RESCALE(pA)
        const float wA = __expf(pA - m);
        UPDATE(xA, wA)
        RESCALE(pB)
        const float wB = __expf(pB - m);
        UPDATE(xB, wB)
    }
    // -------- tail: up to 3 edges (guarded pairs) --------
    for (; base < end_; base += 2) {
        const int ei = base + half_id;
        const bool valid = ei < end_;
        const int eic = valid ? ei : end_ - 1;
        const int s = src_sorted[eic];
        const half8 x = *reinterpret_cast<const half8*>(&hs[(size_t)s * 256 + sl * 8]);
        float p;
        SCORE(x, p)
        p += __shfl_xor(p, 1);
        p += __shfl_xor(p, 2);
        p += __shfl_xor(p, 4);
        if (!valid) p = -INFINITY;
        RESCALE(p)
        const float wv = valid ? __expf(p - m) : 0.0f;
        UPDATE(x, wv)
    }
#undef SCORE
#undef UPDATE
#undef RESCALE

    // -------- merge the two half-waves (xor 32), guarded online merge --------
    {
        const float mo = __shfl_xor(m, 32);
        const float dno = __shfl_xor(den, 32);
        const float M = fmaxf(m, mo);
        const float s1 = (m > -INFINITY) ? __expf(m - M) : 0.0f;
        const float s2 = (mo > -INFINITY) ? __expf(mo - M) : 0.0f;
        den = den * s1 + dno * s2;
#pragma unroll
        for (int j = 0; j < 8; ++j) {
            const float av = __shfl_xor(acc[j], 32);
            acc[j] = acc[j] * s1 + av * s2;
        }
    }

    // -------- epilogue: normalize, ELU, fused layer-2 projection --------
    const float inv = (den > 0.0f) ? 1.0f / den : 0.0f;   // uniform per head group
    float o[8];
#pragma unroll
    for (int j = 0; j < 8; ++j) {
        float v = acc[j] * inv;
        o[j] = (v > 0.0f) ? v : __expf(v) - 1.0f;
    }
    // W2 rows sl*8..sl*8+7: both halves hold identical o -> full-wave sum = 2x truth
    const float4 wsA = *reinterpret_cast<const float4*>(&W2s[sl * 16 + 0]);
    const float4 wsB = *reinterpret_cast<const float4*>(&W2s[sl * 16 + 4]);
    const float4 wsC = *reinterpret_cast<const float4*>(&W2s[sl * 16 + 8]);
    const float4 wsD = *reinterpret_cast<const float4*>(&W2s[sl * 16 + 12]);
    const float4 wdA = *reinterpret_cast<const float4*>(&W2d[sl * 16 + 0]);
    const float4 wdB = *reinterpret_cast<const float4*>(&W2d[sl * 16 + 4]);
    const float4 wdC = *reinterpret_cast<const float4*>(&W2d[sl * 16 + 8]);
    const float4 wdD = *reinterpret_cast<const float4*>(&W2d[sl * 16 + 12]);
    float ps0 = o[0] * wsA.x + o[1] * wsA.z + o[2] * wsB.x + o[3] * wsB.z
              + o[4] * wsC.x + o[5] * wsC.z + o[6] * wsD.x + o[7] * wsD.z;
    float ps1 = o[0] * wsA.y + o[1] * wsA.w + o[2] * wsB.y + o[3] * wsB.w
              + o[4] * wsC.y + o[5] * wsC.w + o[6] * wsD.y + o[7] * wsD.w;
    float pd0 = o[0] * wdA.x + o[1] * wdA.z + o[2] * wdB.x + o[3] * wdB.z
              + o[4] * wdC.x + o[5] * wdC.z + o[6] * wdD.x + o[7] * wdD.z;
    float pd1 = o[0] * wdA.y + o[1] * wdA.w + o[2] * wdB.y + o[3] * wdB.w
              + o[4] * wdC.y + o[5] * wdC.w + o[6] * wdD.y + o[7] * wdD.w;
#pragma unroll
    for (int off = 1; off < 64; off <<= 1) {
        ps0 += __shfl_xor(ps0, off);
        ps1 += __shfl_xor(ps1, off);
        pd0 += __shfl_xor(pd0, off);
        pd1 += __shfl_xor(pd1, off);
    }
    if (lane == 0) {
        hs2[(size_t)n * 2 + 0] = ps0 * 0.5f + b2s[0];
        hs2[(size_t)n * 2 + 1] = ps1 * 0.5f + b2s[1];
        hd2[(size_t)n * 2 + 0] = pd0 * 0.5f + b2d[0];
        hd2[(size_t)n * 2 + 1] = pd1 * 0.5f + b2d[1];
    }
}

// ---------------- Layer-2: 16 lanes per node (deg ~16), 16 nodes per block ----
__global__ __launch_bounds__(256) void node2_kernel(
    const float* __restrict__ hs2, const float* __restrict__ hd2,
    const float* __restrict__ attn2, const int* __restrict__ src_sorted,
    const int* __restrict__ row_start, float* __restrict__ out)
{
    const int n = blockIdx.x * 16 + (threadIdx.x >> 4);
    const int q = threadIdx.x & 15;
    if (n >= NN) return;
    const float a0 = attn2[0], a1 = attn2[1];
    const float h0 = hd2[n * 2 + 0], h1v = hd2[n * 2 + 1];
    const int beg = row_start[n], end_ = row_start[n + 1];
    float m = -INFINITY, den = 0.0f, A0 = 0.0f, A1 = 0.0f;
    for (int i = beg + q; i < end_; i += 16) {
        const int s = src_sorted[i];
        float x0 = hs2[s * 2 + 0], x1 = hs2[s * 2 + 1];
        float t0 = x0 + h0;  t0 = fmaxf(t0, NEG * t0);
        float t1 = x1 + h1v; t1 = fmaxf(t1, NEG * t1);
        float p = fmaf(t0, a0, t1 * a1);
        float mn = fmaxf(m, p);
        float c = __expf(m - mn);
        float w = __expf(p - mn);
        den = den * c + w;
        A0 = A0 * c + w * x0;
        A1 = A1 * c + w * x1;
        m = mn;
    }
#pragma unroll
    for (int off = 1; off < 16; off <<= 1) {
        float m2 = __shfl_xor(m, off, 16);
        float d2 = __shfl_xor(den, off, 16);
        float b0 = __shfl_xor(A0, off, 16);
        float b1 = __shfl_xor(A1, off, 16);
        float mn = fmaxf(m, m2);
        float c1 = (m < mn) ? __expf(m - mn) : 1.0f;
        float c2 = (m2 < mn) ? __expf(m2 - mn) : 1.0f;
        den = den * c1 + d2 * c2;
        A0 = A0 * c1 + b0 * c2;
        A1 = A1 * c1 + b1 * c2;
        m = mn;
    }
    if (q == 0) {
        out[n * 2 + 0] = (den > 0.0f) ? A0 / den : 0.0f;
        out[n * 2 + 1] = (den > 0.0f) ? A1 / den : 0.0f;
    }
}

// ---------------- launch ----------------
extern "C" void kernel_launch(void* const* d_in, const int* in_sizes, int n_in,
                              void* d_out, int out_size, void* d_ws, size_t ws_size,
                              hipStream_t stream)
{
    const float* feat  = (const float*)d_in[0];
    const int*   src   = (const int*)d_in[1];
    const int*   dst   = (const int*)d_in[2];
    const float* W1s   = (const float*)d_in[3];
    const float* b1s   = (const float*)d_in[4];
    const float* W1d   = (const float*)d_in[5];
    const float* b1d   = (const float*)d_in[6];
    const float* attn1 = (const float*)d_in[7];
    const float* W2s   = (const float*)d_in[8];
    const float* b2s   = (const float*)d_in[9];
    const float* W2d   = (const float*)d_in[10];
    const float* b2d   = (const float*)d_in[11];
    const float* attn2 = (const float*)d_in[12];
    float* out = (float*)d_out;

    char* ws = (char*)d_ws;
    size_t off = 0;
    auto alloc = [&](size_t bytes) {
        char* p = ws + off;
        off += (bytes + 255) & ~size_t(255);
        return p;
    };
    _Float16* hs1h       = (_Float16*)alloc((size_t)NN * 256 * 2);
    _Float16* hd1h       = (_Float16*)alloc((size_t)NN * 256 * 2);
    _Float16* wfs        = (_Float16*)alloc((size_t)128 * 256 * 2);
    _Float16* wfd        = (_Float16*)alloc((size_t)128 * 256 * 2);
    int*      src_sorted = (int*)alloc((size_t)NE * 4);
    int*      row_start  = (int*)alloc((size_t)(NN + 1) * 4);
    int*      deg        = (int*)alloc((size_t)NN * 4);
    int*      cursor     = (int*)alloc((size_t)NN * 4);
    int*      bsum       = (int*)alloc((size_t)NB * 4);
    float*    hs2        = (float*)alloc((size_t)NN * 2 * 4);
    float*    hd2        = (float*)alloc((size_t)NN * 2 * 4);
    (void)ws_size; (void)n_in; (void)in_sizes; (void)out_size;

    hipMemsetAsync(deg, 0, (size_t)NN * 4, stream);

    // ---- projections on matrix cores (fp16, one pass for S and D) ----
    dim3 wgrid(128, 2);
    cvt_w<<<wgrid, 256, 0, stream>>>(W1s, W1d, wfs, wfd);
    gemm_mfma<<<(NN + 63) / 64, 256, 0, stream>>>(feat, wfs, b1s, hs1h,
                                                  wfd, b1d, hd1h);

    // ---- CSR build ----
    const int eb = (NE + 255) / 256;
    count_deg<<<eb, 256, 0, stream>>>(dst, deg);
    deg_blocksum<<<NB, 256, 0, stream>>>(deg, bsum);
    scan_bsum<<<1, 256, 0, stream>>>(bsum);
    write_rows<<<NB, 256, 0, stream>>>(deg, bsum, row_start, cursor);
    scatter_src<<<eb, 256, 0, stream>>>(src, dst, cursor, src_sorted);

    gat1_fused<<<NN / 4, 256, 0, stream>>>(hs1h, hd1h, attn1, src_sorted, row_start,
                                           W2s, b2s, W2d, b2d, hs2, hd2);

    node2_kernel<<<(NN + 15) / 16, 256, 0, stream>>>(hs2, hd2, attn2, src_sorted,
                                                     row_start, out);
}

// Round 19
// 213.556 us; speedup vs baseline: 1.1363x; 1.1363x over previous
//
#include <hip/hip_runtime.h>
#include <math.h>

#define NN 50000
#define NE 800000
#define NEG 0.2f
#define NB 196  // ceil(NN/256)

typedef __attribute__((ext_vector_type(4))) float f32x4;
typedef __attribute__((ext_vector_type(8))) _Float16 half8;

#define PAIR(v, k) (__builtin_shufflevector(v, v, 2 * (k), 2 * (k) + 1))

// ---- repack W [128][256] f32 -> MFMA fragment order [ks][ct][lane][8], fp16 ----
__global__ __launch_bounds__(256) void cvt_w(
    const float* __restrict__ Ws, const float* __restrict__ Wd,
    _Float16* __restrict__ Sfrag, _Float16* __restrict__ Dfrag)
{
    const int idx = blockIdx.x * 256 + threadIdx.x;   // 0..32767
    const float* W = blockIdx.y ? Wd : Ws;
    _Float16* o = blockIdx.y ? Dfrag : Sfrag;
    const int j  = idx & 7;
    const int l  = (idx >> 3) & 63;
    const int ct = (idx >> 9) & 15;
    const int ks = idx >> 13;
    const int k   = ks * 32 + ((l >> 4) << 3) + j;
    const int col = (ct << 4) + (l & 15);
    o[idx] = (_Float16)W[(size_t)k * 256 + col];
}

// ---- dual GEMM on matrix cores (fp16 single-term, f32 accumulate).
//      W ks-chunks staged in LDS (16 KB = 1024 uint4, 4/thread).
//      gridDim.y selects S or D projection; both outputs fp16.
__global__ __launch_bounds__(256) void gemm_mfma(
    const float* __restrict__ feat,
    const _Float16* __restrict__ WfS, const float* __restrict__ bS,
    _Float16* __restrict__ outS,
    const _Float16* __restrict__ WfD, const float* __restrict__ bD,
    _Float16* __restrict__ outD)
{
    const _Float16* Wf = blockIdx.y ? WfD : WfS;
    const float* bv = blockIdx.y ? bD : bS;
    _Float16* outp = blockIdx.y ? outD : outS;

    __shared__ uint4 ldsW[1024];   // 16 KB: current ks chunk of W fragments

    const int tid = threadIdx.x;
    const int w   = tid >> 6;        // wave -> rows w*16..+15
    const int l   = tid & 63;
    const int r16 = l & 15;          // A row within tile
    const int kg  = l >> 4;          // k-group (8 wide)
    const int row0 = blockIdx.x * 64;

    int arow = row0 + w * 16 + r16;
    if (arow >= NN) arow = NN - 1;   // clamp (stores guarded)

    f32x4 acc[16];
#pragma unroll
    for (int ct = 0; ct < 16; ++ct) acc[ct] = (f32x4){0.f, 0.f, 0.f, 0.f};

    for (int ks = 0; ks < 4; ++ks) {
        // ---- issue staging + A loads (overlap previous chunk's MFMAs) ----
        const uint4* srcW = reinterpret_cast<const uint4*>(Wf + ks * 8192);
        const uint4 s0 = srcW[tid],       s1 = srcW[256 + tid];
        const uint4 s2 = srcW[512 + tid], s3 = srcW[768 + tid];
        const float4 fa = *reinterpret_cast<const float4*>(
            &feat[(size_t)arow * 128 + ks * 32 + kg * 8]);
        const float4 fb = *reinterpret_cast<const float4*>(
            &feat[(size_t)arow * 128 + ks * 32 + kg * 8 + 4]);

        __syncthreads();             // previous chunk fully consumed
        ldsW[tid] = s0; ldsW[256 + tid] = s1;
        ldsW[512 + tid] = s2; ldsW[768 + tid] = s3;
        __syncthreads();

        // ---- convert A to fp16 in-register ----
        half8 ah;
        ah[0] = (_Float16)fa.x; ah[1] = (_Float16)fa.y;
        ah[2] = (_Float16)fa.z; ah[3] = (_Float16)fa.w;
        ah[4] = (_Float16)fb.x; ah[5] = (_Float16)fb.y;
        ah[6] = (_Float16)fb.z; ah[7] = (_Float16)fb.w;

        const half8* bp = reinterpret_cast<const half8*>(&ldsW[0]);
#pragma unroll
        for (int ct = 0; ct < 16; ++ct) {
            const half8 bh = bp[ct * 64 + l];   // ds_read_b128, conflict-free
            acc[ct] = __builtin_amdgcn_mfma_f32_16x16x32_f16(ah, bh, acc[ct], 0, 0, 0);
        }
    }

    // D layout: col = ct*16 + (lane&15), row = w*16 + (lane>>4)*4 + reg
    const int orow0 = row0 + w * 16 + kg * 4;
#pragma unroll
    for (int ct = 0; ct < 16; ++ct) {
        const int col = ct * 16 + r16;
        const float bias = bv[col];
#pragma unroll
        for (int reg = 0; reg < 4; ++reg) {
            const int orow = orow0 + reg;
            if (orow < NN)
                outp[(size_t)orow * 256 + col] = (_Float16)(acc[ct][reg] + bias);
        }
    }
}

// ---------------- CSR build ----------------
__global__ void count_deg(const int* __restrict__ dst, int* __restrict__ deg)
{
    int e = blockIdx.x * blockDim.x + threadIdx.x;
    if (e < NE) atomicAdd(&deg[dst[e]], 1);
}

__global__ __launch_bounds__(256) void deg_blocksum(const int* __restrict__ deg,
                                                    int* __restrict__ bsum)
{
    int i = blockIdx.x * 256 + threadIdx.x;
    int v = (i < NN) ? deg[i] : 0;
#pragma unroll
    for (int off = 32; off; off >>= 1) v += __shfl_xor(v, off);
    __shared__ int ws[4];
    if ((threadIdx.x & 63) == 0) ws[threadIdx.x >> 6] = v;
    __syncthreads();
    if (threadIdx.x == 0) bsum[blockIdx.x] = ws[0] + ws[1] + ws[2] + ws[3];
}

__global__ __launch_bounds__(256) void scan_bsum(int* __restrict__ bsum)
{
    __shared__ int tmp[256];
    int t = threadIdx.x;
    int orig = (t < NB) ? bsum[t] : 0;
    tmp[t] = orig;
    __syncthreads();
    for (int off = 1; off < 256; off <<= 1) {
        int v = (t >= off) ? tmp[t - off] : 0;
        __syncthreads();
        tmp[t] += v;
        __syncthreads();
    }
    if (t < NB) bsum[t] = tmp[t] - orig;  // exclusive prefix
}

__global__ __launch_bounds__(256) void write_rows(const int* __restrict__ deg,
                                                  const int* __restrict__ bpre,
                                                  int* __restrict__ row_start,
                                                  int* __restrict__ cursor)
{
    int i = blockIdx.x * 256 + threadIdx.x;
    int d = (i < NN) ? deg[i] : 0;
    int lane = threadIdx.x & 63, w = threadIdx.x >> 6;
    int x = d;
#pragma unroll
    for (int off = 1; off < 64; off <<= 1) {
        int v = __shfl_up(x, off);
        if (lane >= off) x += v;
    }
    __shared__ int wsum[4];
    if (lane == 63) wsum[w] = x;
    __syncthreads();
    int woff = 0;
#pragma unroll
    for (int k = 0; k < 4; ++k)
        if (k < w) woff += wsum[k];
    if (i < NN) {
        int rs = bpre[blockIdx.x] + woff + x - d;
        row_start[i] = rs;
        cursor[i] = rs;
    }
    if (blockIdx.x == 0 && threadIdx.x == 0) row_start[NN] = NE;
}

// cursor pre-initialized to row_start values -> absolute positions
__global__ void scatter_src(const int* __restrict__ src, const int* __restrict__ dst,
                            int* __restrict__ cursor, int* __restrict__ src_sorted)
{
    int e = blockIdx.x * blockDim.x + threadIdx.x;
    if (e < NE) {
        int pos = atomicAdd(&cursor[dst[e]], 1);
        src_sorted[pos] = src[e];
    }
}

// ---- Layer-1 fused: WAVE = NODE, 32 lanes per edge (2 edges/iter, x2 unroll).
//      lane = 8 contiguous dims (16B fp16 load); packed-fp16 score; f32 accum.
__global__ __launch_bounds__(256) void gat1_fused(
    const _Float16* __restrict__ hs, const _Float16* __restrict__ hd,
    const float* __restrict__ attn, const int* __restrict__ src_sorted,
    const int* __restrict__ row_start,
    const float* __restrict__ W2s, const float* __restrict__ b2s,
    const float* __restrict__ W2d, const float* __restrict__ b2d,
    float* __restrict__ hs2, float* __restrict__ hd2)
{
    const int n = blockIdx.x * 4 + (threadIdx.x >> 6);   // NN % 4 == 0
    const int lane = threadIdx.x & 63;
    const int half_id = lane >> 5;     // which edge of the pair
    const int sl = lane & 31;          // dims sl*8 .. sl*8+7 (head = sl>>3)
    const int beg = row_start[n], end_ = row_start[n + 1];

    // this lane's 8 dims of attn (converted) and hd (already fp16)
    const float4 af0 = *reinterpret_cast<const float4*>(&attn[sl * 8 + 0]);
    const float4 af1 = *reinterpret_cast<const float4*>(&attn[sl * 8 + 4]);
    half8 ah;
    ah[0] = (_Float16)af0.x; ah[1] = (_Float16)af0.y; ah[2] = (_Float16)af0.z; ah[3] = (_Float16)af0.w;
    ah[4] = (_Float16)af1.x; ah[5] = (_Float16)af1.y; ah[6] = (_Float16)af1.z; ah[7] = (_Float16)af1.w;
    const half8 yh = *reinterpret_cast<const half8*>(&hd[(size_t)n * 256 + sl * 8]);
    const _Float16 NEGH = (_Float16)NEG;

    float m = -INFINITY, den = 0.0f;
    float acc[8];
#pragma unroll
    for (int j = 0; j < 8; ++j) acc[j] = 0.0f;

#define SCORE(xh, p)                                                         \
    {                                                                        \
        half8 t = xh + yh;                                                   \
        half8 tn = t * NEGH;                                                 \
        t = __builtin_elementwise_max(t, tn);                                \
        p = __builtin_amdgcn_fdot2(PAIR(t, 0), PAIR(ah, 0), 0.0f, false);    \
        p = __builtin_amdgcn_fdot2(PAIR(t, 1), PAIR(ah, 1), p, false);       \
        p = __builtin_amdgcn_fdot2(PAIR(t, 2), PAIR(ah, 2), p, false);       \
        p = __builtin_amdgcn_fdot2(PAIR(t, 3), PAIR(ah, 3), p, false);       \
    }
#define UPDATE(xh, wv)                                                       \
    {                                                                        \
        den += wv;                                                           \
        _Pragma("unroll")                                                    \
        for (int j = 0; j < 8; ++j)                                          \
            acc[j] = fmaf(wv, (float)xh[j], acc[j]);                         \
    }
#define RESCALE(p)                                                           \
    if (p > m + 8.0f) {                                                      \
        const float rs = __expf(m - p);                                      \
        den *= rs;                                                           \
        _Pragma("unroll")                                                    \
        for (int j = 0; j < 8; ++j) acc[j] *= rs;                            \
        m = p;                                                               \
    }

    int base = beg;
    // -------- main loop: 4 edges per iter (2 per half-wave, 2 gathers in flight) ----
    for (; base + 3 < end_; base += 4) {
        const int sA = src_sorted[base + half_id];
        const int sB = src_sorted[base + 2 + half_id];
        const half8 xA = *reinterpret_cast<const half8*>(&hs[(size_t)sA * 256 + sl * 8]);
        const half8 xB = *reinterpret_cast<const half8*>(&hs[(size_t)sB * 256 + sl * 8]);
        float pA, pB;
        SCORE(xA, pA)
        SCORE(xB, pB)
        pA += __shfl_xor(pA, 1);  pB += __shfl_xor(pB, 1);
        pA += __shfl_xor(pA, 2);  pB += __shfl_xor(pB, 2);
        pA += __shfl_xor(pA, 4);  pB += __shfl_xor(pB, 4);
        RESCALE(pA)
        const float wA = __expf(pA - m);
        UPDATE(xA, wA)
        RESCALE(pB)
        const float wB = __expf(pB - m);
        UPDATE(xB, wB)
    }
    // -------- tail: up to 3 edges (guarded pairs) --------
    for (; base < end_; base += 2) {
        const int ei = base + half_id;
        const bool valid = ei < end_;
        const int eic = valid ? ei : end_ - 1;
        const int s = src_sorted[eic];
        const half8 x = *reinterpret_cast<const half8*>(&hs[(size_t)s * 256 + sl * 8]);
        float p;
        SCORE(x, p)
        p += __shfl_xor(p, 1);
        p += __shfl_xor(p, 2);
        p += __shfl_xor(p, 4);
        if (!valid) p = -INFINITY;
        RESCALE(p)
        const float wv = valid ? __expf(p - m) : 0.0f;
        UPDATE(x, wv)
    }
#undef SCORE
#undef UPDATE
#undef RESCALE

    // -------- merge the two half-waves (xor 32), guarded online merge --------
    {
        const float mo = __shfl_xor(m, 32);
        const float dno = __shfl_xor(den, 32);
        const float M = fmaxf(m, mo);
        const float s1 = (m > -INFINITY) ? __expf(m - M) : 0.0f;
        const float s2 = (mo > -INFINITY) ? __expf(mo - M) : 0.0f;
        den = den * s1 + dno * s2;
#pragma unroll
        for (int j = 0; j < 8; ++j) {
            const float av = __shfl_xor(acc[j], 32);
            acc[j] = acc[j] * s1 + av * s2;
        }
    }

    // -------- epilogue: normalize, ELU, fused layer-2 projection --------
    const float inv = (den > 0.0f) ? 1.0f / den : 0.0f;   // uniform per head group
    float o[8];
#pragma unroll
    for (int j = 0; j < 8; ++j) {
        float v = acc[j] * inv;
        o[j] = (v > 0.0f) ? v : __expf(v) - 1.0f;
    }
    // W2 rows sl*8..sl*8+7: both halves hold identical o -> full-wave sum = 2x truth
    const float4 wsA = *reinterpret_cast<const float4*>(&W2s[sl * 16 + 0]);
    const float4 wsB = *reinterpret_cast<const float4*>(&W2s[sl * 16 + 4]);
    const float4 wsC = *reinterpret_cast<const float4*>(&W2s[sl * 16 + 8]);
    const float4 wsD = *reinterpret_cast<const float4*>(&W2s[sl * 16 + 12]);
    const float4 wdA = *reinterpret_cast<const float4*>(&W2d[sl * 16 + 0]);
    const float4 wdB = *reinterpret_cast<const float4*>(&W2d[sl * 16 + 4]);
    const float4 wdC = *reinterpret_cast<const float4*>(&W2d[sl * 16 + 8]);
    const float4 wdD = *reinterpret_cast<const float4*>(&W2d[sl * 16 + 12]);
    float ps0 = o[0] * wsA.x + o[1] * wsA.z + o[2] * wsB.x + o[3] * wsB.z
              + o[4] * wsC.x + o[5] * wsC.z + o[6] * wsD.x + o[7] * wsD.z;
    float ps1 = o[0] * wsA.y + o[1] * wsA.w + o[2] * wsB.y + o[3] * wsB.w
              + o[4] * wsC.y + o[5] * wsC.w + o[6] * wsD.y + o[7] * wsD.w;
    float pd0 = o[0] * wdA.x + o[1] * wdA.z + o[2] * wdB.x + o[3] * wdB.z
              + o[4] * wdC.x + o[5] * wdC.z + o[6] * wdD.x + o[7] * wdD.z;
    float pd1 = o[0] * wdA.y + o[1] * wdA.w + o[2] * wdB.y + o[3] * wdB.w
              + o[4] * wdC.y + o[5] * wdC.w + o[6] * wdD.y + o[7] * wdD.w;
#pragma unroll
    for (int off = 1; off < 64; off <<= 1) {
        ps0 += __shfl_xor(ps0, off);
        ps1 += __shfl_xor(ps1, off);
        pd0 += __shfl_xor(pd0, off);
        pd1 += __shfl_xor(pd1, off);
    }
    if (lane == 0) {
        hs2[(size_t)n * 2 + 0] = ps0 * 0.5f + b2s[0];
        hs2[(size_t)n * 2 + 1] = ps1 * 0.5f + b2s[1];
        hd2[(size_t)n * 2 + 0] = pd0 * 0.5f + b2d[0];
        hd2[(size_t)n * 2 + 1] = pd1 * 0.5f + b2d[1];
    }
}

// ---------------- Layer-2: 16 lanes per node (deg ~16), 16 nodes per block ----
__global__ __launch_bounds__(256) void node2_kernel(
    const float* __restrict__ hs2, const float* __restrict__ hd2,
    const float* __restrict__ attn2, const int* __restrict__ src_sorted,
    const int* __restrict__ row_start, float* __restrict__ out)
{
    const int n = blockIdx.x * 16 + (threadIdx.x >> 4);
    const int q = threadIdx.x & 15;
    if (n >= NN) return;
    const float a0 = attn2[0], a1 = attn2[1];
    const float h0 = hd2[n * 2 + 0], h1v = hd2[n * 2 + 1];
    const int beg = row_start[n], end_ = row_start[n + 1];
    float m = -INFINITY, den = 0.0f, A0 = 0.0f, A1 = 0.0f;
    for (int i = beg + q; i < end_; i += 16) {
        const int s = src_sorted[i];
        float x0 = hs2[s * 2 + 0], x1 = hs2[s * 2 + 1];
        float t0 = x0 + h0;  t0 = fmaxf(t0, NEG * t0);
        float t1 = x1 + h1v; t1 = fmaxf(t1, NEG * t1);
        float p = fmaf(t0, a0, t1 * a1);
        float mn = fmaxf(m, p);
        float c = __expf(m - mn);
        float w = __expf(p - mn);
        den = den * c + w;
        A0 = A0 * c + w * x0;
        A1 = A1 * c + w * x1;
        m = mn;
    }
#pragma unroll
    for (int off = 1; off < 16; off <<= 1) {
        float m2 = __shfl_xor(m, off, 16);
        float d2 = __shfl_xor(den, off, 16);
        float b0 = __shfl_xor(A0, off, 16);
        float b1 = __shfl_xor(A1, off, 16);
        float mn = fmaxf(m, m2);
        float c1 = (m < mn) ? __expf(m - mn) : 1.0f;
        float c2 = (m2 < mn) ? __expf(m2 - mn) : 1.0f;
        den = den * c1 + d2 * c2;
        A0 = A0 * c1 + b0 * c2;
        A1 = A1 * c1 + b1 * c2;
        m = mn;
    }
    if (q == 0) {
        out[n * 2 + 0] = (den > 0.0f) ? A0 / den : 0.0f;
        out[n * 2 + 1] = (den > 0.0f) ? A1 / den : 0.0f;
    }
}

// ---------------- launch ----------------
extern "C" void kernel_launch(void* const* d_in, const int* in_sizes, int n_in,
                              void* d_out, int out_size, void* d_ws, size_t ws_size,
                              hipStream_t stream)
{
    const float* feat  = (const float*)d_in[0];
    const int*   src   = (const int*)d_in[1];
    const int*   dst   = (const int*)d_in[2];
    const float* W1s   = (const float*)d_in[3];
    const float* b1s   = (const float*)d_in[4];
    const float* W1d   = (const float*)d_in[5];
    const float* b1d   = (const float*)d_in[6];
    const float* attn1 = (const float*)d_in[7];
    const float* W2s   = (const float*)d_in[8];
    const float* b2s   = (const float*)d_in[9];
    const float* W2d   = (const float*)d_in[10];
    const float* b2d   = (const float*)d_in[11];
    const float* attn2 = (const float*)d_in[12];
    float* out = (float*)d_out;

    char* ws = (char*)d_ws;
    size_t off = 0;
    auto alloc = [&](size_t bytes) {
        char* p = ws + off;
        off += (bytes + 255) & ~size_t(255);
        return p;
    };
    _Float16* hs1h       = (_Float16*)alloc((size_t)NN * 256 * 2);
    _Float16* hd1h       = (_Float16*)alloc((size_t)NN * 256 * 2);
    _Float16* wfs        = (_Float16*)alloc((size_t)128 * 256 * 2);
    _Float16* wfd        = (_Float16*)alloc((size_t)128 * 256 * 2);
    int*      src_sorted = (int*)alloc((size_t)NE * 4);
    int*      row_start  = (int*)alloc((size_t)(NN + 1) * 4);
    int*      deg        = (int*)alloc((size_t)NN * 4);
    int*      cursor     = (int*)alloc((size_t)NN * 4);
    int*      bsum       = (int*)alloc((size_t)NB * 4);
    float*    hs2        = (float*)alloc((size_t)NN * 2 * 4);
    float*    hd2        = (float*)alloc((size_t)NN * 2 * 4);
    (void)ws_size; (void)n_in; (void)in_sizes; (void)out_size;

    hipMemsetAsync(deg, 0, (size_t)NN * 4, stream);

    // ---- projections on matrix cores (fp16 single-term, split S/D passes) ----
    dim3 wgrid(128, 2);
    cvt_w<<<wgrid, 256, 0, stream>>>(W1s, W1d, wfs, wfd);
    dim3 ggrid((NN + 63) / 64, 2);
    gemm_mfma<<<ggrid, 256, 0, stream>>>(feat, wfs, b1s, hs1h, wfd, b1d, hd1h);

    // ---- CSR build ----
    const int eb = (NE + 255) / 256;
    count_deg<<<eb, 256, 0, stream>>>(dst, deg);
    deg_blocksum<<<NB, 256, 0, stream>>>(deg, bsum);
    scan_bsum<<<1, 256, 0, stream>>>(bsum);
    write_rows<<<NB, 256, 0, stream>>>(deg, bsum, row_start, cursor);
    scatter_src<<<eb, 256, 0, stream>>>(src, dst, cursor, src_sorted);

    gat1_fused<<<NN / 4, 256, 0, stream>>>(hs1h, hd1h, attn1, src_sorted, row_start,
                                           W2s, b2s, W2d, b2d, hs2, hd2);

    node2_kernel<<<(NN + 15) / 16, 256, 0, stream>>>(hs2, hd2, attn2, src_sorted,
                                                     row_start, out);
}